// Round 17
// baseline (82.446 us; speedup 1.0000x reference)
//
#include <hip/hip_runtime.h>
#include <stdint.h>

typedef unsigned short u16;
typedef __attribute__((ext_vector_type(8))) short short8;
typedef __attribute__((ext_vector_type(4))) float f32x4;

#define BATCH 4
#define SEQ   2048
#define DIN   768
#define DK    128
#define DV    768
#define MTOT  (BATCH*SEQ)   // 8192
#define NQKV  1024          // 128 q + 128 k + 768 v

__device__ __forceinline__ u16 f2bf(float f) {
  union { float f; uint32_t u; } v; v.f = f;
  uint32_t r = v.u + 0x7FFFu + ((v.u >> 16) & 1u);
  return (u16)(r >> 16);
}

template<int N> __device__ __forceinline__ void wait_vmcnt() {
  if constexpr (N == 0) asm volatile("s_waitcnt vmcnt(0)" ::: "memory");
  else if constexpr (N == 3) asm volatile("s_waitcnt vmcnt(3)" ::: "memory");
  else if constexpr (N == 6) asm volatile("s_waitcnt vmcnt(6)" ::: "memory");
}

#define GLOAD_LDS(SRC, DST) \
  __builtin_amdgcn_global_load_lds( \
      (const __attribute__((address_space(1))) unsigned int*)(SRC), \
      (__attribute__((address_space(3))) unsigned int*)(DST), 16, 0, 0)

// ---------------- K0: prep = convert_x + pack weights/bias ----------------
__global__ __launch_bounds__(256) void prep(
    const float* __restrict__ x, u16* __restrict__ xb,
    const float* __restrict__ Wq, const float* __restrict__ bq,
    const float* __restrict__ Wk, const float* __restrict__ bk,
    const float* __restrict__ Wv, const float* __restrict__ bv,
    u16* __restrict__ WbT, float* __restrict__ biasP) {
  const float qs = 0.088388347648318447f;  // 1/sqrt(128)
  __shared__ u16 tile[64][72];
  int b = blockIdx.x;
  int tid = threadIdx.x;
  if (b < 6144) {               // convert x -> bf16
    int i = (b * 256 + tid) * 4;
    float4 v = *(const float4*)(x + i);
    u16 o[4] = { f2bf(v.x), f2bf(v.y), f2bf(v.z), f2bf(v.w) };
    *(uint2*)(xb + i) = *(const uint2*)o;
    return;
  }
  int bid2 = b - 6144;          // 0..191 : pack weights (12 x 16)
  int y   = bid2 / 12;
  int i0  = (bid2 - y * 12) * 64;
  const float* W; u16* dst; int ldw, nb; float sc;
  if (y < 2)      { W = Wq; dst = WbT;                      ldw = DK; sc = qs;   nb = y;     }
  else if (y < 4) { W = Wk; dst = WbT + (size_t)DK * DIN;   ldw = DK; sc = 1.0f; nb = y - 2; }
  else            { W = Wv; dst = WbT + (size_t)2*DK * DIN; ldw = DV; sc = 1.0f; nb = y - 4; }
  int n0 = nb * 64;
  if (i0 == 0 && y == 0) {
    for (int n = tid; n < NQKV; n += 256)
      biasP[n] = (n < DK) ? bq[n] * qs : (n < 2*DK ? bk[n - DK] : bv[n - 2*DK]);
  }
  int tr = tid >> 2;
  int tc = (tid & 3) * 16;
  const float* src = W + (size_t)(i0 + tr) * ldw + n0 + tc;
  u16 o[16];
#pragma unroll
  for (int u = 0; u < 16; u += 4) {
    float4 v = *(const float4*)(src + u);
    o[u] = f2bf(v.x * sc); o[u+1] = f2bf(v.y * sc); o[u+2] = f2bf(v.z * sc); o[u+3] = f2bf(v.w * sc);
  }
  *(uint4*)&tile[tr][tc]     = *(const uint4*)&o[0];
  *(uint4*)&tile[tr][tc + 8] = *(const uint4*)&o[8];
  __syncthreads();
  u16 tmp[16];
#pragma unroll
  for (int u = 0; u < 16; ++u) tmp[u] = tile[tc + u][tr];
  u16* d = dst + (size_t)(n0 + tr) * DIN + i0 + tc;
  *(uint4*)d       = *(const uint4*)&tmp[0];
  *(uint4*)(d + 8) = *(const uint4*)&tmp[8];
}

// ---------------- proj GEMM: 128x256 tile, 3-slot counted-vmcnt(6) ring ----------------
__global__ __launch_bounds__(512, 2) void gemm_proj(
    const u16* __restrict__ A, const u16* __restrict__ BT,
    u16* __restrict__ C0, u16* __restrict__ C1,
    const float* __restrict__ bias)
{
  const int NT = DIN / 64;             // 12 K-tiles
  __shared__ u16 As[3][128][64];       // 48 KB
  __shared__ u16 Bs[3][256][64];       // 96 KB
  const int tid = threadIdx.x;
  const int l   = tid & 63;
  const int wid = tid >> 6;
  const int wm  = wid >> 2;
  const int wn  = wid & 3;

  const int nwg = gridDim.x;           // 256
  const int cpx = nwg >> 3;
  const int bid = blockIdx.x;
  const int wg  = (bid & 7) * cpx + (bid >> 3);
  const int by  = wg >> 6;
  const int bx  = wg & 63;
  const int m0  = bx * 128;
  const int n0  = by * 256;

  f32x4 acc[4][4] = {};
  const int lr = l >> 3;
  const int lc = ((l & 7) ^ lr) * 8;

  auto STAGE = [&](int buf, int k0, int i0r, int i1r) {
#pragma unroll
    for (int i = 0; i < 6; ++i) {
      if (i < i0r || i >= i1r) continue;
      int c = wid * 6 + i;
      if (c < 16) {
        GLOAD_LDS(A + (size_t)(m0 + c * 8 + lr) * DIN + k0 + lc, &As[buf][c * 8][0]);
      } else {
        int cb = c - 16;
        GLOAD_LDS(BT + (size_t)(n0 + cb * 8 + lr) * DIN + k0 + lc, &Bs[buf][cb * 8][0]);
      }
    }
  };

  STAGE(0, 0, 0, 6);
  STAGE(1, 64, 0, 6);
  int cur = 0;
  for (int t = 0; t < NT; ++t) {
    if (t == NT - 1) wait_vmcnt<0>(); else wait_vmcnt<6>();
    __builtin_amdgcn_s_barrier();
    const int nxt2 = (cur + 2 >= 3) ? cur - 1 : cur + 2;
    const bool pf = (t + 2 < NT);
#pragma unroll
    for (int ks = 0; ks < 2; ++ks) {
      short8 af[4], bg[4];
#pragma unroll
      for (int i = 0; i < 4; ++i) {
        int row  = wm * 64 + i * 16 + (l & 15);
        int slot = (ks * 4 + (l >> 4)) ^ (row & 7);
        af[i] = *(const short8*)&As[cur][row][slot * 8];
      }
#pragma unroll
      for (int j = 0; j < 4; ++j) {
        int row  = wn * 64 + j * 16 + (l & 15);
        int slot = (ks * 4 + (l >> 4)) ^ (row & 7);
        bg[j] = *(const short8*)&Bs[cur][row][slot * 8];
      }
      if (pf) {
        if (ks == 0) STAGE(nxt2, (t + 2) * 64, 0, 3);
        else         STAGE(nxt2, (t + 2) * 64, 3, 6);
      }
      __builtin_amdgcn_s_setprio(1);
#pragma unroll
      for (int i = 0; i < 4; ++i)
#pragma unroll
        for (int j = 0; j < 4; ++j)
          acc[i][j] = __builtin_amdgcn_mfma_f32_16x16x32_bf16(af[i], bg[j], acc[i][j], 0, 0, 0);
      __builtin_amdgcn_s_setprio(0);
    }
    cur = (cur + 1 == 3) ? 0 : cur + 1;
  }

  const int rbase = (l >> 4) * 4;
  const int cl    = l & 15;
#pragma unroll
  for (int i = 0; i < 4; ++i) {
#pragma unroll
    for (int j = 0; j < 4; ++j) {
      int col  = n0 + wn * 64 + j * 16 + cl;
      int row0 = m0 + wm * 64 + i * 16 + rbase;
      float bv_ = bias[col];
      if (by == 0) {
#pragma unroll
        for (int q = 0; q < 4; ++q)
          C0[(size_t)(row0 + q) * 256 + col] = f2bf(acc[i][j][q] + bv_);
      } else {
        int b = row0 >> 11, t = row0 & 2047;
        u16 o[4];
#pragma unroll
        for (int q = 0; q < 4; ++q) o[q] = f2bf(acc[i][j][q] + bv_);
        *(uint2*)&C1[((size_t)b * DV + (col - 256)) * SEQ + t] = *(const uint2*)o;
      }
    }
  }
}

// ---------------- K3: S-GEMM 256x256: P_t = exp(q_s @ k^T) in FRAGMENT-TILED layout ----------------
// P_t[q16][t32][lane][8]: PV loads af fragments with one coalesced dwordx4.
__global__ __launch_bounds__(512, 2) void sgemm_exp(
    const u16* __restrict__ qk, u16* __restrict__ Pt)
{
  __shared__ u16 As[256][128];
  __shared__ u16 Bs[256][128];
  const int tid = threadIdx.x;
  const int l   = tid & 63;
  const int wid = tid >> 6;
  const int wm  = wid >> 2;            // 0..1 : 128-row half
  const int wn  = wid & 3;             // 0..3 : 64-col quarter

  const int nwg = gridDim.x;           // 256
  const int cpx = nwg >> 3;
  const int bid = blockIdx.x;
  const int wg  = (bid & 7) * cpx + (bid >> 3);
  const int z   = wg >> 6;
  const int rem = wg & 63;
  const int by  = rem >> 3;
  const int bx  = rem & 7;
  const int m0  = bx * 256;
  const int n0  = by * 256;

  const u16* A  = qk + (size_t)z * SEQ * 256;
  const u16* BT = qk + DK + (size_t)z * SEQ * 256;

  const int rin = l >> 4;
  const int s16 = l & 15;
#pragma unroll
  for (int i = 0; i < 16; ++i) {
    int c = wid * 16 + i;
    if (c < 64) {
      int r = c * 4 + rin;
      int gs = s16 ^ (r & 7);
      GLOAD_LDS(A + (size_t)(m0 + r) * 256 + gs * 8, &As[c * 4][0]);
    } else {
      int cb = c - 64;
      int r = cb * 4 + rin;
      int gs = s16 ^ (r & 7);
      GLOAD_LDS(BT + (size_t)(n0 + r) * 256 + gs * 8, &Bs[cb * 4][0]);
    }
  }
  __syncthreads();

  f32x4 acc[8][4] = {};
#pragma unroll
  for (int ks = 0; ks < 4; ++ks) {
    short8 af[8], bg[4];
#pragma unroll
    for (int i = 0; i < 8; ++i) {
      int row  = wm * 128 + i * 16 + (l & 15);
      int slot = (ks * 4 + (l >> 4)) ^ (row & 7);
      af[i] = *(const short8*)&As[row][slot * 8];
    }
#pragma unroll
    for (int j = 0; j < 4; ++j) {
      int row  = wn * 64 + j * 16 + (l & 15);
      int slot = (ks * 4 + (l >> 4)) ^ (row & 7);
      bg[j] = *(const short8*)&Bs[row][slot * 8];
    }
#pragma unroll
    for (int i = 0; i < 8; ++i)
#pragma unroll
      for (int j = 0; j < 4; ++j)
        acc[i][j] = __builtin_amdgcn_mfma_f32_16x16x32_bf16(af[i], bg[j], acc[i][j], 0, 0, 0);
  }

  __syncthreads();                     // done reading As/Bs; reuse as repack region
  u16* region = (wid < 4) ? (&As[0][0] + wid * 8192) : (&Bs[0][0] + (wid - 4) * 8192);
#pragma unroll
  for (int i = 0; i < 8; ++i)
#pragma unroll
    for (int j = 0; j < 4; ++j)
#pragma unroll
      for (int q = 0; q < 4; ++q) {
        int lq  = i * 16 + (l >> 4) * 4 + q;
        int lt  = j * 16 + (l & 15);
        int col = (((lt >> 3) ^ (lq & 7)) << 3) | (lt & 7);
        region[lq * 64 + col] = f2bf(__expf(acc[i][j][q]));
      }
  __syncthreads();
  u16* Pz = (u16*)Pt + (size_t)z * SEQ * SEQ;
#pragma unroll
  for (int i = 0; i < 8; ++i)
#pragma unroll
    for (int jj = 0; jj < 2; ++jj) {
      int lq   = i * 16 + (l & 15);
      int slot = (jj * 4 + (l >> 4)) ^ (lq & 7);
      uint4 v  = *(const uint4*)&region[lq * 64 + slot * 8];
      int gq16 = (m0 >> 4) + wm * 8 + i;
      int gt32 = (n0 >> 5) + wn * 2 + jj;
      *(uint4*)&Pz[((size_t)(gq16 * 64 + gt32) * 64 + l) * 8] = v;
    }
}

// ---------------- PV GEMM: af direct-from-global (fragment-tiled P), B-only LDS ----------------
__global__ __launch_bounds__(512, 2) void gemm_pv(
    const u16* __restrict__ Pt, const u16* __restrict__ vT,
    float* __restrict__ out)
{
  const int NT = SEQ / 64;             // 32
  __shared__ u16 Bs[3][192][64];       // 72 KB
  const int tid = threadIdx.x;
  const int l   = tid & 63;
  const int wid = tid >> 6;
  const int wm  = wid >> 2;            // 0..1
  const int wn  = wid & 3;             // 0..3

  const int nwg = gridDim.x;           // 256
  const int cpx = nwg >> 3;
  const int bid = blockIdx.x;
  const int wg  = (bid & 7) * cpx + (bid >> 3);
  const int z   = wg >> 6;
  const int rem = wg & 63;
  const int by  = rem / 16;
  const int bx  = rem & 15;
  const int m0  = bx * 128;
  const int n0  = by * 192;

  const u16* Ptz = Pt + (size_t)z * SEQ * SEQ;
  const u16* BT  = vT + (size_t)z * DV * SEQ;

  f32x4 acc[4][3] = {};
  f32x4 accO[4] = {};
  const short8 kOnes = {16256,16256,16256,16256,16256,16256,16256,16256};

  const int lr = l >> 3;
  const int lc = ((l & 7) ^ lr) * 8;

  auto STAGE_B = [&](int buf, int t0) {
#pragma unroll
    for (int i = 0; i < 3; ++i) {
      int c = wid * 3 + i;             // 0..23
      GLOAD_LDS(BT + (size_t)(n0 + c * 8 + lr) * SEQ + t0 * 64 + lc, &Bs[buf][c * 8][0]);
    }
  };

  uint4 afA[4][2], afB[4][2];
  auto AFLOAD = [&](uint4 (&dst)[4][2], int t) {
#pragma unroll
    for (int i = 0; i < 4; ++i)
#pragma unroll
      for (int ks = 0; ks < 2; ++ks) {
        const u16* p = Ptz + ((size_t)((bx * 8 + wm * 4 + i) * 64 + (2 * t + ks)) * 64 + l) * 8;
        asm volatile("global_load_dwordx4 %0, %1, off"
                     : "=v"(dst[i][ks]) : "v"(p) : "memory");
      }
  };

  auto BODY = [&](uint4 (&af)[4][2], uint4 (&afn)[4][2], int t) {
    if (t == NT - 1) wait_vmcnt<0>(); else wait_vmcnt<3>();
    __builtin_amdgcn_sched_barrier(0);
    __builtin_amdgcn_s_barrier();
    if (t + 1 < NT) AFLOAD(afn, t + 1);
    const int buf = t % 3;
#pragma unroll
    for (int ks = 0; ks < 2; ++ks) {
      short8 bg[3];
#pragma unroll
      for (int j = 0; j < 3; ++j) {
        int row  = wn * 48 + j * 16 + (l & 15);
        int slot = (ks * 4 + (l >> 4)) ^ (row & 7);
        bg[j] = *(const short8*)&Bs[buf][row][slot * 8];
      }
      __builtin_amdgcn_s_setprio(1);
#pragma unroll
      for (int i = 0; i < 4; ++i) {
        short8 a = *(const short8*)&af[i][ks];
#pragma unroll
        for (int j = 0; j < 3; ++j)
          acc[i][j] = __builtin_amdgcn_mfma_f32_16x16x32_bf16(a, bg[j], acc[i][j], 0, 0, 0);
        accO[i] = __builtin_amdgcn_mfma_f32_16x16x32_bf16(a, kOnes, accO[i], 0, 0, 0);
      }
      __builtin_amdgcn_s_setprio(0);
    }
    if (t + 2 < NT) STAGE_B((t + 2) % 3, t + 2);
    __builtin_amdgcn_s_barrier();
  };

  AFLOAD(afA, 0);                      // af first: FIFO -> vmcnt(3) retires AF0+B0
  STAGE_B(0, 0);
  STAGE_B(1, 1);
  for (int t = 0; t < NT; t += 2) {
    BODY(afA, afB, t);
    BODY(afB, afA, t + 1);
  }

  const int rbase = (l >> 4) * 4;
  const int cl    = l & 15;
#pragma unroll
  for (int i = 0; i < 4; ++i) {
    int row0 = m0 + wm * 64 + i * 16 + rbase;
    f32x4 rs;
#pragma unroll
    for (int q = 0; q < 4; ++q) rs[q] = 1.0f / accO[i][q];
#pragma unroll
    for (int j = 0; j < 3; ++j) {
      int col = n0 + wn * 48 + j * 16 + cl;
#pragma unroll
      for (int q = 0; q < 4; ++q)
        out[(size_t)z * SEQ * DV + (size_t)(row0 + q) * DV + col] = acc[i][j][q] * rs[q];
    }
  }
}

extern "C" void kernel_launch(void* const* d_in, const int* in_sizes, int n_in,
                              void* d_out, int out_size, void* d_ws, size_t ws_size,
                              hipStream_t stream) {
  const float* x  = (const float*)d_in[0];
  const float* Wq = (const float*)d_in[1];
  const float* bq = (const float*)d_in[2];
  const float* Wk = (const float*)d_in[3];
  const float* bk = (const float*)d_in[4];
  const float* Wv = (const float*)d_in[5];
  const float* bv = (const float*)d_in[6];
  float* out = (float*)d_out;

  size_t off = 0;
  auto alloc = [&](size_t bytes) -> void* {
    void* p = (char*)d_ws + off;
    off += (bytes + 255) & ~(size_t)255;
    return p;
  };
  u16*   xb    = (u16*)alloc((size_t)MTOT * DIN * 2);
  u16*   WbT   = (u16*)alloc((size_t)NQKV * DIN * 2);
  float* biasP = (float*)alloc(NQKV * 4);
  u16*   qk    = (u16*)alloc((size_t)MTOT * 256 * 2);
  u16*   vT    = (u16*)alloc((size_t)BATCH * DV * SEQ * 2);
  u16*   Pt    = (u16*)alloc((size_t)BATCH * SEQ * SEQ * 2);
  if (off > ws_size) return;

  prep<<<dim3(6144 + 192), dim3(256), 0, stream>>>(x, xb, Wq, bq, Wk, bk, Wv, bv, WbT, biasP);

  // proj: [8192,1024] = xb @ WbT^T + bias; 128x256 tile, 3-slot ring
  gemm_proj<<<dim3(64 * 4), dim3(512), 0, stream>>>(xb, WbT, qk, vT, biasP);

  // P_t = exp(q_scaled @ k^T) per batch, 256x256, fragment-tiled output
  sgemm_exp<<<dim3(8 * 8 * BATCH), dim3(512), 0, stream>>>(qk, Pt);

  // out = (P @ vT^T) / rowsum(P) per batch; af direct-from-global
  gemm_pv<<<dim3(16 * 4 * BATCH), dim3(512), 0, stream>>>(Pt, vT, out);
}